// Round 7
// baseline (196.790 us; speedup 1.0000x reference)
//
#include <hip/hip_runtime.h>

// Problem constants (fixed by setup_inputs)
constexpr int kB = 256;      // batch
constexpr int kN = 128;      // seq len
constexpr int kM = 512;      // mem width
constexpr int kSlots = 15;   // his_mem slots
constexpr int kS = 16;       // slots incl. null
constexpr int kW = 1536;     // attn_W row length (d_q + M)
constexpr int kSeg = 16;     // per-batch cached ambiguous-step capacity

__device__ __forceinline__ float tanh_fast(float x)
{
    float xc = fminf(15.f, fmaxf(-15.f, x));
    float ex = __expf(2.f * xc);
    return 1.f - 2.f * __builtin_amdgcn_rcpf(ex + 1.f);
}

// ---------------------------------------------------------------------------
// prep1: one block per batch. Empty-slot flags, bulk hm copy, gumbel filter,
// default one-hot(15) log rows, and per-batch ambiguous-step segment built by
// ballot compaction (ascending t, no atomics, no zero-init needed).
// ---------------------------------------------------------------------------
__global__ __launch_bounds__(256) void prep1_k(
    const float* __restrict__ his_mem, const float* __restrict__ null_mem,
    const float* __restrict__ gumbel_u, float* __restrict__ out,
    int* __restrict__ empty0, int* __restrict__ cnt, int* __restrict__ ambList,
    unsigned char* __restrict__ amb_flags)
{
    const int b = blockIdx.x;
    const int tid = threadIdx.x;
    const int wave = tid >> 6, lane = tid & 63;
    __shared__ int eflag[kS];
    __shared__ int wcnt[4];
    float* out_hm = out;
    float* out_log = out + (size_t)kB * kSlots * kM;

    // empty flags + hm copy: each of 4 waves handles 4 slot-rows
    for (int s = wave; s < kS; s += 4) {
        const float* p = (s < kSlots) ? his_mem + (size_t)(b * kSlots + s) * kM
                                      : null_mem + (size_t)b * kM;
        float4 v0 = *(const float4*)(p + lane * 4);
        float4 v1 = *(const float4*)(p + 256 + lane * 4);
        int nz = (v0.x != 0.f) | (v0.y != 0.f) | (v0.z != 0.f) | (v0.w != 0.f) |
                 (v1.x != 0.f) | (v1.y != 0.f) | (v1.z != 0.f) | (v1.w != 0.f);
        unsigned long long bal = __ballot(nz);
        if (lane == 0) eflag[s] = (bal == 0ull) ? 1 : 0;
        if (s < kSlots) {
            float* dst = out_hm + (size_t)(b * kSlots + s) * kM;
            *(float4*)(dst + lane * 4) = v0;
            *(float4*)(dst + 256 + lane * 4) = v1;
        }
    }
    __syncthreads();
    if (tid < kS) empty0[b * kS + tid] = eflag[tid];

    // filter: threads 0..127 each own step t = tid
    bool amb = false;
    if (tid < kN) {
        const int idx = b * kN + tid;
        const float* up = gumbel_u + (size_t)idx * kS;
        float g[kS];
#pragma unroll
        for (int s = 0; s < kS; ++s) {
            float u = fminf(fmaxf(up[s], 1e-20f), 1.0f);
            g[s] = -logf(-logf(u) + 1e-20f);
        }
        float rhs = g[15] + 10.f * (eflag[15] ? 1.f : 0.f) - 1.01f;
#pragma unroll
        for (int s = 0; s < kSlots; ++s)
            amb = amb || (g[s] + 10.f * (eflag[s] ? 1.f : 0.f) >= rhs);
        amb_flags[idx] = amb ? 1 : 0;
        float* lp = out_log + (size_t)idx * kS;
        float4 zz = make_float4(0.f, 0.f, 0.f, 0.f);
        *(float4*)(lp + 0) = zz;
        *(float4*)(lp + 4) = zz;
        *(float4*)(lp + 8) = zz;
        *(float4*)(lp + 12) = make_float4(0.f, 0.f, 0.f, 1.f);
    }
    // ballot compaction: ascending-t segment order (wave0 then wave1)
    unsigned long long bal = __ballot(amb);     // waves 2,3 contribute 0
    if (lane == 0) wcnt[wave] = __popcll(bal);
    __syncthreads();
    if (tid < kN && amb) {
        int j = __popcll(bal & ((1ull << lane) - 1)) + (wave == 1 ? wcnt[0] : 0);
        if (j < kSeg) ambList[b * kSeg + j] = tid;
    }
    if (tid == 0) cnt[b] = wcnt[0] + wcnt[1];
}

// ---------------------------------------------------------------------------
// prep2: blocks 0..2047 = c0 tiles (b = x>>3, 64-col tile), blocks
// 2048..6143 = qcw chunks (b = (x-2048)>>4, 32-row chunk). Inactive batches
// (cnt==0) exit immediately. No compacted lists, no counters.
// ---------------------------------------------------------------------------
__global__ __launch_bounds__(256) void prep2_k(
    const float* __restrict__ W, const float* __restrict__ his_mem,
    const float* __restrict__ null_mem, const float* __restrict__ states,
    const float* __restrict__ global_trace, const float* __restrict__ attn_b,
    const int* __restrict__ cnt, const int* __restrict__ ambList,
    float* __restrict__ C0, float* __restrict__ qCache,
    float* __restrict__ cwCache, int* __restrict__ stepNz)
{
    const int tid = threadIdx.x;
    __shared__ float sbuf[kS * 520];   // c0: staged mem[b]; qcw: Xs (first 1024)
    __shared__ int nzs;

    if (blockIdx.x < 2048) {
        // ---------------- c0 path: C0[b,s][col] = W3[col] . mem[b,s] -------
        const int b = blockIdx.x >> 3;
        if (cnt[b] == 0) return;
        const int n0 = (blockIdx.x & 7) * 64;
        for (int i = tid; i < kS * (kM / 4); i += 256) {
            int s = i >> 7;
            int c4 = (i & 127) * 4;
            const float* p = (s < kSlots) ? his_mem + (size_t)(b * kSlots + s) * kM
                                          : null_mem + (size_t)b * kM;
            *(float4*)&sbuf[s * 520 + c4] = *(const float4*)(p + c4);
        }
        __syncthreads();
        const int g = tid >> 4, l = tid & 15;
#pragma unroll
        for (int cc = 0; cc < 4; ++cc) {
            const int col = n0 + cc * 16 + g;
            const float* wr = W + (size_t)col * kW + 1024;
            float acc[kS];
#pragma unroll
            for (int s = 0; s < kS; ++s) acc[s] = 0.f;
#pragma unroll 2
            for (int jj = 0; jj < 8; ++jj) {
                int k = l * 4 + jj * 64;
                float4 w4 = *(const float4*)(wr + k);
#pragma unroll
                for (int s = 0; s < kS; ++s) {
                    float4 m4 = *(const float4*)&sbuf[s * 520 + k];
                    acc[s] = fmaf(w4.x, m4.x, acc[s]);
                    acc[s] = fmaf(w4.y, m4.y, acc[s]);
                    acc[s] = fmaf(w4.z, m4.z, acc[s]);
                    acc[s] = fmaf(w4.w, m4.w, acc[s]);
                }
            }
#pragma unroll
            for (int s = 0; s < kS; ++s) {
                acc[s] += __shfl_xor(acc[s], 1);
                acc[s] += __shfl_xor(acc[s], 2);
                acc[s] += __shfl_xor(acc[s], 4);
                acc[s] += __shfl_xor(acc[s], 8);
            }
            if (l == 0) {
#pragma unroll
                for (int s = 0; s < kS; ++s)
                    C0[(size_t)(b * kS + s) * kM + col] = acc[s];
            }
        }
    } else {
        // ---------------- qcw path: q and cw rows for cached steps ---------
        const int u = (int)blockIdx.x - 2048;
        const int b = u >> 4;
        const int j = u & 15;            // 32-row chunk
        int nc = cnt[b];
        if (nc == 0) return;
        if (nc > kSeg) nc = kSeg;

        for (int i = 0; i < nc; ++i) {
            const int t = ambList[b * kSeg + i];
            const int idx = b * kN + t;
            __syncthreads();             // protect sbuf reuse across steps
            if (tid == 0) nzs = 0;
            __syncthreads();
            float s0 = states[(size_t)idx * kM + tid];
            float s1 = states[(size_t)idx * kM + 256 + tid];
            sbuf[tid] = s0; sbuf[256 + tid] = s1;
            sbuf[512 + tid] = global_trace[(size_t)b * kM + tid];
            sbuf[768 + tid] = global_trace[(size_t)b * kM + 256 + tid];
            if (s0 != 0.f || s1 != 0.f) nzs = 1;
            __syncthreads();

            const int g = tid >> 4, l = tid & 15;
#pragma unroll
            for (int p = 0; p < 2; ++p) {
                const int r = j * 32 + p * 16 + g;
                const float* wr = W + (size_t)r * kW;
                float accq = 0.f, accc = 0.f;
#pragma unroll
                for (int jj = 0; jj < 16; ++jj) {
                    int k = l * 4 + jj * 64;
                    float4 w4 = *(const float4*)(wr + k);
                    float4 x4 = *(const float4*)&sbuf[k];
                    accq = fmaf(w4.x, x4.x, accq); accq = fmaf(w4.y, x4.y, accq);
                    accq = fmaf(w4.z, x4.z, accq); accq = fmaf(w4.w, x4.w, accq);
                }
#pragma unroll
                for (int jj = 0; jj < 8; ++jj) {
                    int k = l * 4 + jj * 64;
                    float4 w4 = *(const float4*)(wr + 1024 + k);
                    float4 x4 = *(const float4*)&sbuf[k];
                    accc = fmaf(w4.x, x4.x, accc); accc = fmaf(w4.y, x4.y, accc);
                    accc = fmaf(w4.z, x4.z, accc); accc = fmaf(w4.w, x4.w, accc);
                }
                accq += __shfl_xor(accq, 1); accq += __shfl_xor(accq, 2);
                accq += __shfl_xor(accq, 4); accq += __shfl_xor(accq, 8);
                accc += __shfl_xor(accc, 1); accc += __shfl_xor(accc, 2);
                accc += __shfl_xor(accc, 4); accc += __shfl_xor(accc, 8);
                if (l == 0) {
                    qCache[(size_t)(b * kSeg + i) * kM + r] = accq + attn_b[r];
                    cwCache[(size_t)(b * kSeg + i) * kM + r] = accc;
                }
            }
            if (tid == 0 && j == 0) stepNz[b * kSeg + i] = nzs;
        }
    }
}

// ---------------------------------------------------------------------------
// Phase B: per ambiguous batch, walk flagged steps in ascending t. The local
// flagged-step counter jloc indexes the per-batch cache segment directly.
// (Inline recompute fallback only if jloc >= kSeg — never with real input.)
// ---------------------------------------------------------------------------
constexpr int kCsStride = 528;   // 512+16 -> at most 2-way bank aliasing (free)

__global__ __launch_bounds__(256) void phaseB_k(
    const float* __restrict__ C0, const int* __restrict__ empty0,
    const unsigned char* __restrict__ amb_flags, const int* __restrict__ cnt,
    const float* __restrict__ qCache, const float* __restrict__ cwCache,
    const int* __restrict__ stepNz, const float* __restrict__ states,
    const float* __restrict__ states_mask, const float* __restrict__ gumbel_u,
    const float* __restrict__ global_trace, const float* __restrict__ W,
    const float* __restrict__ attn_b, const float* __restrict__ v,
    float* __restrict__ out)
{
    const int b = blockIdx.x;
    if (cnt[b] == 0) return;     // defaults already correct
    const int tid = threadIdx.x;
    float* out_hm = out;
    float* out_log = out + (size_t)kB * kSlots * kM;

    __shared__ float Cs[kS * kCsStride];
    __shared__ float Xb[1024];          // [state | gt] — fallback path only
    __shared__ float Qb[kM];            // fallback q
    __shared__ float vs[kM];
    __shared__ float e_sh[kS];
    __shared__ float empty_sh[kS];
    __shared__ unsigned char flS[kN];
    __shared__ int slot_src[kSlots];
    __shared__ int k_sh, wk_sh, nz_sh;

    for (int i = tid; i < kS * kM; i += 256) {
        int s = i >> 9, m = i & 511;
        Cs[s * kCsStride + m] = C0[(size_t)(b * kS + s) * kM + m];
    }
    for (int i = tid; i < kM; i += 256) {
        vs[i] = v[i];
        Xb[512 + i] = global_trace[(size_t)b * kM + i];
    }
    if (tid < kS) empty_sh[tid] = empty0[b * kS + tid] ? 1.0f : 0.0f;
    if (tid < kSlots) slot_src[tid] = -1;
    if (tid < kN) flS[tid] = amb_flags[b * kN + tid];
    __syncthreads();

    const int sidx = tid >> 4;   // slot handled by this thread
    const int ml = tid & 15;     // lane within slot group

    int jloc = 0;
    for (int t = 0; t < kN; ++t) {
        if (!flS[t]) continue;
        const bool cached = (jloc < kSeg);
        const int pos = b * kSeg + jloc;
        ++jloc;

        const float* qp;
        if (cached) {
            qp = qCache + (size_t)pos * kM;
        } else {
            // fallback: recompute q inline (dead code for real inputs)
            Xb[tid] = states[(size_t)(b * kN + t) * kM + tid];
            Xb[256 + tid] = states[(size_t)(b * kN + t) * kM + 256 + tid];
            __syncthreads();
            const int g2 = tid >> 4, l2 = tid & 15;
            for (int r0 = 0; r0 < kM; r0 += 16) {
                int r = r0 + g2;
                const float* wr = W + (size_t)r * kW;
                float a = 0.f;
                for (int k = l2 * 4; k < 1024; k += 64) {
                    float4 w4 = *(const float4*)(wr + k);
                    float4 x4 = *(const float4*)&Xb[k];
                    a = fmaf(w4.x, x4.x, a); a = fmaf(w4.y, x4.y, a);
                    a = fmaf(w4.z, x4.z, a); a = fmaf(w4.w, x4.w, a);
                }
                a += __shfl_xor(a, 1); a += __shfl_xor(a, 2);
                a += __shfl_xor(a, 4); a += __shfl_xor(a, 8);
                if (l2 == 0) Qb[r] = a + attn_b[r];
            }
            __syncthreads();
            qp = Qb;
        }

        // e[s] = sum_m v[m] * tanh(q[m] + C[s][m]); float4, 16 lanes/slot
        const float* crow = &Cs[sidx * kCsStride];
        float acc = 0.f;
#pragma unroll
        for (int j = 0; j < 8; ++j) {
            int m = ml * 4 + j * 64;
            float4 q4 = *(const float4*)(qp + m);
            float4 c4 = *(const float4*)&crow[m];
            float4 v4 = *(const float4*)&vs[m];
            acc = fmaf(v4.x, tanh_fast(q4.x + c4.x), acc);
            acc = fmaf(v4.y, tanh_fast(q4.y + c4.y), acc);
            acc = fmaf(v4.z, tanh_fast(q4.z + c4.z), acc);
            acc = fmaf(v4.w, tanh_fast(q4.w + c4.w), acc);
        }
        acc += __shfl_xor(acc, 1); acc += __shfl_xor(acc, 2);
        acc += __shfl_xor(acc, 4); acc += __shfl_xor(acc, 8);
        if (ml == 0) e_sh[sidx] = acc;
        __syncthreads();

        // wave 0: softmax + empty mask + gumbel + argmax
        if (tid < 64) {
            int s = tid;
            float ev = (s < kS) ? e_sh[s] : -3.0e38f;
            float mx = ev;
            mx = fmaxf(mx, __shfl_xor(mx, 1));
            mx = fmaxf(mx, __shfl_xor(mx, 2));
            mx = fmaxf(mx, __shfl_xor(mx, 4));
            mx = fmaxf(mx, __shfl_xor(mx, 8));
            float w = (s < kS) ? __expf(ev - mx) : 0.f;
            float sm = w;
            sm += __shfl_xor(sm, 1); sm += __shfl_xor(sm, 2);
            sm += __shfl_xor(sm, 4); sm += __shfl_xor(sm, 8);
            w = w / sm;
            w += 10.0f * ((s < kS) ? empty_sh[s] : 0.f);
            float z;
            if (s < kS) {
                float u = gumbel_u[(size_t)(b * kN + t) * kS + s];
                u = fminf(fmaxf(u, 1e-20f), 1.0f);
                float g = -logf(-logf(u) + 1e-20f);
                z = w + g;            // tau = 1.0
            } else z = -3.0e38f;
            float zm = z;
            zm = fmaxf(zm, __shfl_xor(zm, 1));
            zm = fmaxf(zm, __shfl_xor(zm, 2));
            zm = fmaxf(zm, __shfl_xor(zm, 4));
            zm = fmaxf(zm, __shfl_xor(zm, 8));
            unsigned long long bal = __ballot(z == zm) & 0xFFFFull;
            if (s == 0) k_sh = __ffsll(bal) - 1;   // first-max (jnp.argmax)
        }
        __syncthreads();

        const int k = k_sh;
        if (tid < kS) out_log[(size_t)(b * kN + t) * kS + tid] = (tid == k) ? 1.f : 0.f;
        if (tid == 0) {
            float mv = states_mask[b * kN + t];
            wk_sh = (k < kSlots && mv != 0.0f) ? k : -1;
            nz_sh = 0;
        }
        __syncthreads();

        const int wk = wk_sh;
        if (wk >= 0) {
            if (cached) {
                // cached: C-row copy + precomputed nz flag
                Cs[wk * kCsStride + tid] = cwCache[(size_t)pos * kM + tid];
                Cs[wk * kCsStride + 256 + tid] = cwCache[(size_t)pos * kM + 256 + tid];
                if (tid == 0) {
                    slot_src[wk] = t;
                    empty_sh[wk] = stepNz[pos] ? 0.f : 1.f;
                }
            } else {
                // fallback: inline cw GEMV from staged Xb (dead code normally)
                if (Xb[tid] != 0.f || Xb[256 + tid] != 0.f) nz_sh = 1;
                __syncthreads();
                const int g2 = tid >> 4, l2 = tid & 15;
                for (int r0 = 0; r0 < kM; r0 += 16) {
                    int r = r0 + g2;
                    const float* wr = W + (size_t)r * kW + 1024;
                    float ca = 0.f;
                    for (int k2 = l2 * 4; k2 < kM; k2 += 64) {
                        float4 w4 = *(const float4*)(wr + k2);
                        float4 x4 = *(const float4*)&Xb[k2];
                        ca = fmaf(w4.x, x4.x, ca); ca = fmaf(w4.y, x4.y, ca);
                        ca = fmaf(w4.z, x4.z, ca); ca = fmaf(w4.w, x4.w, ca);
                    }
                    ca += __shfl_xor(ca, 1); ca += __shfl_xor(ca, 2);
                    ca += __shfl_xor(ca, 4); ca += __shfl_xor(ca, 8);
                    if (l2 == 0) Cs[wk * kCsStride + r] = ca;
                }
                __syncthreads();
                if (tid == 0) {
                    slot_src[wk] = t;
                    empty_sh[wk] = nz_sh ? 0.f : 1.f;
                }
            }
        }
        __syncthreads();
    }

    // epilogue: overwrite written slots only (bulk copy already done)
    for (int s = 0; s < kSlots; ++s) {
        int ts = slot_src[s];
        if (ts >= 0) {
            float* dst = out_hm + (size_t)(b * kSlots + s) * kM;
            dst[tid] = states[(size_t)(b * kN + ts) * kM + tid];
            dst[tid + 256] = states[(size_t)(b * kN + ts) * kM + tid + 256];
        }
    }
}

// ---------------------------------------------------------------------------
extern "C" void kernel_launch(void* const* d_in, const int* in_sizes, int n_in,
                              void* d_out, int out_size, void* d_ws, size_t ws_size,
                              hipStream_t stream)
{
    const float* his_mem      = (const float*)d_in[0];
    const float* states       = (const float*)d_in[1];
    const float* states_mask  = (const float*)d_in[2];
    const float* global_trace = (const float*)d_in[3];
    const float* null_mem     = (const float*)d_in[4];
    const float* gumbel_u     = (const float*)d_in[5];
    const float* attn_W       = (const float*)d_in[6];
    const float* attn_b       = (const float*)d_in[7];
    const float* v            = (const float*)d_in[8];

    // ws layout (~24.2 MB), every cell written before read (no zero-init):
    //   C0      [4096*512] f32   (8 MB)
    //   qCache  [256*16*512] f32 (8 MB)
    //   cwCache [256*16*512] f32 (8 MB)
    //   empty0[4096] i32 | cnt[256] i32 | ambList[4096] i32 | stepNz[4096] i32
    //   amb[32768] u8
    float* C0 = (float*)d_ws;
    float* qCache = C0 + (size_t)kB * kS * kM;
    float* cwCache = qCache + (size_t)kB * kSeg * kM;
    int* empty0 = (int*)(cwCache + (size_t)kB * kSeg * kM);
    int* cnt = empty0 + kB * kS;
    int* ambList = cnt + kB;
    int* stepNz = ambList + kB * kSeg;
    unsigned char* amb = (unsigned char*)(stepNz + kB * kSeg);

    prep1_k<<<kB, 256, 0, stream>>>(his_mem, null_mem, gumbel_u, (float*)d_out,
                                    empty0, cnt, ambList, amb);
    prep2_k<<<6144, 256, 0, stream>>>(attn_W, his_mem, null_mem, states,
                                      global_trace, attn_b, cnt, ambList,
                                      C0, qCache, cwCache, stepNz);
    phaseB_k<<<kB, 256, 0, stream>>>(C0, empty0, amb, cnt, qCache, cwCache,
                                     stepNz, states, states_mask, gumbel_u,
                                     global_trace, attn_W, attn_b, v,
                                     (float*)d_out);
}

// Round 8
// 170.134 us; speedup vs baseline: 1.1567x; 1.1567x over previous
//
#include <hip/hip_runtime.h>

// Problem constants (fixed by setup_inputs)
constexpr int kB = 256;      // batch
constexpr int kN = 128;      // seq len
constexpr int kM = 512;      // mem width
constexpr int kSlots = 15;   // his_mem slots
constexpr int kS = 16;       // slots incl. null
constexpr int kW = 1536;     // attn_W row length (d_q + M)
constexpr int kCap = 8192;   // cached ambiguous-step capacity (n~66 measured)

__device__ __forceinline__ float tanh_fast(float x)
{
    float xc = fminf(15.f, fmaxf(-15.f, x));
    float ex = __expf(2.f * xc);
    return 1.f - 2.f * __builtin_amdgcn_rcpf(ex + 1.f);
}

// ---------------------------------------------------------------------------
// prep1: one block per batch. Fuses: empty-slot flags, bulk hm copy
// (out_hm = his_mem), gumbel ambiguity filter, default one-hot(15) log rows,
// and compact list building. cnt/total zeroed by a preceding hipMemsetAsync.
// ---------------------------------------------------------------------------
__global__ __launch_bounds__(256) void prep1_k(
    const float* __restrict__ his_mem, const float* __restrict__ null_mem,
    const float* __restrict__ gumbel_u, float* __restrict__ out,
    int* __restrict__ empty0, int* __restrict__ cnt, int* __restrict__ total,
    unsigned* __restrict__ list, int* __restrict__ listPos,
    int* __restrict__ ambBatch, unsigned char* __restrict__ amb_flags)
{
    const int b = blockIdx.x;
    const int tid = threadIdx.x;
    const int wave = tid >> 6, lane = tid & 63;
    __shared__ int eflag[kS];
    float* out_hm = out;
    float* out_log = out + (size_t)kB * kSlots * kM;

    // empty flags + hm copy: each of 4 waves handles 4 slot-rows
    for (int s = wave; s < kS; s += 4) {
        const float* p = (s < kSlots) ? his_mem + (size_t)(b * kSlots + s) * kM
                                      : null_mem + (size_t)b * kM;
        float4 v0 = *(const float4*)(p + lane * 4);
        float4 v1 = *(const float4*)(p + 256 + lane * 4);
        int nz = (v0.x != 0.f) | (v0.y != 0.f) | (v0.z != 0.f) | (v0.w != 0.f) |
                 (v1.x != 0.f) | (v1.y != 0.f) | (v1.z != 0.f) | (v1.w != 0.f);
        unsigned long long bal = __ballot(nz);
        if (lane == 0) eflag[s] = (bal == 0ull) ? 1 : 0;
        if (s < kSlots) {
            float* dst = out_hm + (size_t)(b * kSlots + s) * kM;
            *(float4*)(dst + lane * 4) = v0;
            *(float4*)(dst + 256 + lane * 4) = v1;
        }
    }
    __syncthreads();
    if (tid < kS) empty0[b * kS + tid] = eflag[tid];

    // filter: threads 0..127 each own step t = tid
    if (tid < kN) {
        const int idx = b * kN + tid;
        const float* up = gumbel_u + (size_t)idx * kS;
        float g[kS];
#pragma unroll
        for (int s = 0; s < kS; ++s) {
            float u = fminf(fmaxf(up[s], 1e-20f), 1.0f);
            g[s] = -logf(-logf(u) + 1e-20f);
        }
        float rhs = g[15] + 10.f * (eflag[15] ? 1.f : 0.f) - 1.01f;
        bool amb = false;
#pragma unroll
        for (int s = 0; s < kSlots; ++s)
            amb = amb || (g[s] + 10.f * (eflag[s] ? 1.f : 0.f) >= rhs);
        amb_flags[idx] = amb ? 1 : 0;
        if (amb) {
            int pos = atomicAdd(&total[0], 1);
            if (pos < kCap) list[pos] = (unsigned)idx;
            listPos[idx] = pos;
            int prev = atomicAdd(&cnt[b], 1);
            if (prev == 0) {
                int bp = atomicAdd(&total[1], 1);
                ambBatch[bp] = b;
            }
        }
        float* lp = out_log + (size_t)idx * kS;
        float4 zz = make_float4(0.f, 0.f, 0.f, 0.f);
        *(float4*)(lp + 0) = zz;
        *(float4*)(lp + 4) = zz;
        *(float4*)(lp + 8) = zz;
        *(float4*)(lp + 12) = make_float4(0.f, 0.f, 0.f, 1.f);
    }
}

// ---------------------------------------------------------------------------
// prep2: fused c0-GEMM (blocks 0..511) + qcw GEMV chunks (blocks 512..2559).
// The two halves are independent; fusing lets them overlap on one stream.
//
// c0 path: C0[b*16+s][m] = W[m][1024:1536] . mem[b,s], gathered over the
//   compacted ambiguous-batch list (4 batches = 64 rows per x-tile).
// qcw path: per cached ambiguous step i and 32-row chunk j:
//   q[r]  = bias[r] + W[r][0:1024] . [state|gt]
//   cw[r] = W[r][1024:1536] . state      (C-row if this step writes)
//   stepNz[i] = any(state != 0)
// ---------------------------------------------------------------------------
__global__ __launch_bounds__(256) void prep2_k(
    const float* __restrict__ W, const float* __restrict__ his_mem,
    const float* __restrict__ null_mem, const float* __restrict__ states,
    const float* __restrict__ global_trace, const float* __restrict__ attn_b,
    const int* __restrict__ total, const int* __restrict__ ambBatch,
    const unsigned* __restrict__ list, float* __restrict__ C0,
    float* __restrict__ qCache, float* __restrict__ cwCache,
    int* __restrict__ stepNz)
{
    const int tid = threadIdx.x;

    if (blockIdx.x < 512) {
        // ------------------------- c0 GEMM path ---------------------------
        const int nab = total[1];
        const int cx = blockIdx.x >> 3;          // 0..63  (row tiles)
        const int cy = blockIdx.x & 7;           // 0..7   (col tiles)
        if (cx * 4 >= nab) return;
        __shared__ float As[16 * 68];
        __shared__ float Bs[16 * 68];
        const int n0 = cy * 64;
        const int row_l = tid >> 2;
        const int k4 = (tid & 3) * 4;
        const int ty = tid >> 4, tx = tid & 15;

        int bi = cx * 4 + (row_l >> 4);
        if (bi >= nab) bi = nab - 1;             // clamp: redundant work only
        const int b = ambBatch[bi];
        const int s = row_l & 15;
        const float* ap = (s < kSlots) ? (his_mem + (size_t)(b * kSlots + s) * kM)
                                       : (null_mem + (size_t)b * kM);
        const float* wp = W + (size_t)(n0 + row_l) * kW + 1024;

        float acc[4][4];
#pragma unroll
        for (int i = 0; i < 4; ++i)
#pragma unroll
            for (int j = 0; j < 4; ++j) acc[i][j] = 0.f;

        for (int kt = 0; kt < kM; kt += 16) {
            float4 a4 = *(const float4*)(ap + kt + k4);
            float4 b4 = *(const float4*)(wp + kt + k4);
            __syncthreads();
            As[(k4 + 0) * 68 + row_l] = a4.x; As[(k4 + 1) * 68 + row_l] = a4.y;
            As[(k4 + 2) * 68 + row_l] = a4.z; As[(k4 + 3) * 68 + row_l] = a4.w;
            Bs[(k4 + 0) * 68 + row_l] = b4.x; Bs[(k4 + 1) * 68 + row_l] = b4.y;
            Bs[(k4 + 2) * 68 + row_l] = b4.z; Bs[(k4 + 3) * 68 + row_l] = b4.w;
            __syncthreads();
#pragma unroll
            for (int k = 0; k < 16; ++k) {
                const float4 av = *(const float4*)&As[k * 68 + ty * 4];
                const float4 bv = *(const float4*)&Bs[k * 68 + tx * 4];
                acc[0][0] = fmaf(av.x, bv.x, acc[0][0]);
                acc[0][1] = fmaf(av.x, bv.y, acc[0][1]);
                acc[0][2] = fmaf(av.x, bv.z, acc[0][2]);
                acc[0][3] = fmaf(av.x, bv.w, acc[0][3]);
                acc[1][0] = fmaf(av.y, bv.x, acc[1][0]);
                acc[1][1] = fmaf(av.y, bv.y, acc[1][1]);
                acc[1][2] = fmaf(av.y, bv.z, acc[1][2]);
                acc[1][3] = fmaf(av.y, bv.w, acc[1][3]);
                acc[2][0] = fmaf(av.z, bv.x, acc[2][0]);
                acc[2][1] = fmaf(av.z, bv.y, acc[2][1]);
                acc[2][2] = fmaf(av.z, bv.z, acc[2][2]);
                acc[2][3] = fmaf(av.z, bv.w, acc[2][3]);
                acc[3][0] = fmaf(av.w, bv.x, acc[3][0]);
                acc[3][1] = fmaf(av.w, bv.y, acc[3][1]);
                acc[3][2] = fmaf(av.w, bv.z, acc[3][2]);
                acc[3][3] = fmaf(av.w, bv.w, acc[3][3]);
            }
        }
#pragma unroll
        for (int i = 0; i < 4; ++i) {
            int rl = ty * 4 + i;
            int bij = cx * 4 + (rl >> 4);
            if (bij >= nab) bij = nab - 1;
            int ro = ambBatch[bij] * kS + (rl & 15);
            float4 o = make_float4(acc[i][0], acc[i][1], acc[i][2], acc[i][3]);
            *(float4*)(C0 + (size_t)ro * kM + n0 + tx * 4) = o;
        }
    } else {
        // ------------------------- qcw GEMV path --------------------------
        int n = total[0];
        if (n > kCap) n = kCap;
        __shared__ float Xs[1024];
        __shared__ int nzs;

        for (int c = (int)blockIdx.x - 512; c < n * 16; c += 2048) {
            const int i = c >> 4;        // step index in list
            const int j = c & 15;        // 32-row chunk
            const int idx = (int)list[i];
            const int b = idx >> 7;
            __syncthreads();             // protect Xs reuse across iterations
            if (tid == 0) nzs = 0;
            __syncthreads();
            float s0 = states[(size_t)idx * kM + tid];
            float s1 = states[(size_t)idx * kM + 256 + tid];
            Xs[tid] = s0; Xs[256 + tid] = s1;
            Xs[512 + tid] = global_trace[(size_t)b * kM + tid];
            Xs[768 + tid] = global_trace[(size_t)b * kM + 256 + tid];
            if (s0 != 0.f || s1 != 0.f) nzs = 1;
            __syncthreads();

            const int g = tid >> 4;      // 0..15 row group
            const int l = tid & 15;      // lane in group
#pragma unroll
            for (int p = 0; p < 2; ++p) {
                const int r = j * 32 + p * 16 + g;
                const float* wr = W + (size_t)r * kW;
                float accq = 0.f, accc = 0.f;
#pragma unroll
                for (int jj = 0; jj < 16; ++jj) {
                    int k = l * 4 + jj * 64;
                    float4 w4 = *(const float4*)(wr + k);
                    float4 x4 = *(const float4*)&Xs[k];
                    accq = fmaf(w4.x, x4.x, accq); accq = fmaf(w4.y, x4.y, accq);
                    accq = fmaf(w4.z, x4.z, accq); accq = fmaf(w4.w, x4.w, accq);
                }
#pragma unroll
                for (int jj = 0; jj < 8; ++jj) {
                    int k = l * 4 + jj * 64;
                    float4 w4 = *(const float4*)(wr + 1024 + k);
                    float4 x4 = *(const float4*)&Xs[k];
                    accc = fmaf(w4.x, x4.x, accc); accc = fmaf(w4.y, x4.y, accc);
                    accc = fmaf(w4.z, x4.z, accc); accc = fmaf(w4.w, x4.w, accc);
                }
                accq += __shfl_xor(accq, 1); accq += __shfl_xor(accq, 2);
                accq += __shfl_xor(accq, 4); accq += __shfl_xor(accq, 8);
                accc += __shfl_xor(accc, 1); accc += __shfl_xor(accc, 2);
                accc += __shfl_xor(accc, 4); accc += __shfl_xor(accc, 8);
                if (l == 0) {
                    qCache[(size_t)i * kM + r] = accq + attn_b[r];
                    cwCache[(size_t)i * kM + r] = accc;
                }
            }
            if (tid == 0 && j == 0) stepNz[i] = nzs;
        }
    }
}

// ---------------------------------------------------------------------------
// Phase B: per ambiguous batch, walk flagged steps in order. Serial chain is
// W-free: e-eval from qCache + LDS C; writes copy cwCache into LDS.
// (Inline recompute fallback only if listPos >= kCap — never with real input.)
// ---------------------------------------------------------------------------
constexpr int kCsStride = 528;   // 512+16 -> at most 2-way bank aliasing (free)

__global__ __launch_bounds__(256) void phaseB_k(
    const float* __restrict__ C0, const int* __restrict__ empty0,
    const unsigned char* __restrict__ amb_flags, const int* __restrict__ cnt,
    const int* __restrict__ listPos, const float* __restrict__ qCache,
    const float* __restrict__ cwCache, const int* __restrict__ stepNz,
    const float* __restrict__ states, const float* __restrict__ states_mask,
    const float* __restrict__ gumbel_u, const float* __restrict__ global_trace,
    const float* __restrict__ W, const float* __restrict__ attn_b,
    const float* __restrict__ v, float* __restrict__ out)
{
    const int b = blockIdx.x;
    if (cnt[b] == 0) return;     // defaults already correct
    const int tid = threadIdx.x;
    float* out_hm = out;
    float* out_log = out + (size_t)kB * kSlots * kM;

    __shared__ float Cs[kS * kCsStride];
    __shared__ float Xb[1024];          // [state | gt] — fallback path only
    __shared__ float Qb[kM];            // fallback q
    __shared__ float vs[kM];
    __shared__ float e_sh[kS];
    __shared__ float empty_sh[kS];
    __shared__ unsigned char flS[kN];
    __shared__ int slot_src[kSlots];
    __shared__ int k_sh, wk_sh, nz_sh;

    for (int i = tid; i < kS * kM; i += 256) {
        int s = i >> 9, m = i & 511;
        Cs[s * kCsStride + m] = C0[(size_t)(b * kS + s) * kM + m];
    }
    for (int i = tid; i < kM; i += 256) {
        vs[i] = v[i];
        Xb[512 + i] = global_trace[(size_t)b * kM + i];
    }
    if (tid < kS) empty_sh[tid] = empty0[b * kS + tid] ? 1.0f : 0.0f;
    if (tid < kSlots) slot_src[tid] = -1;
    if (tid < kN) flS[tid] = amb_flags[b * kN + tid];
    __syncthreads();

    const int sidx = tid >> 4;   // slot handled by this thread
    const int ml = tid & 15;     // lane within slot group

    for (int t = 0; t < kN; ++t) {
        if (!flS[t]) continue;

        const int pos = listPos[b * kN + t];
        const float* qp;
        if (pos < kCap) {
            qp = qCache + (size_t)pos * kM;
        } else {
            // fallback: recompute q inline (dead code for real inputs)
            Xb[tid] = states[(size_t)(b * kN + t) * kM + tid];
            Xb[256 + tid] = states[(size_t)(b * kN + t) * kM + 256 + tid];
            __syncthreads();
            const int g2 = tid >> 4, l2 = tid & 15;
            for (int r0 = 0; r0 < kM; r0 += 16) {
                int r = r0 + g2;
                const float* wr = W + (size_t)r * kW;
                float a = 0.f;
                for (int k = l2 * 4; k < 1024; k += 64) {
                    float4 w4 = *(const float4*)(wr + k);
                    float4 x4 = *(const float4*)&Xb[k];
                    a = fmaf(w4.x, x4.x, a); a = fmaf(w4.y, x4.y, a);
                    a = fmaf(w4.z, x4.z, a); a = fmaf(w4.w, x4.w, a);
                }
                a += __shfl_xor(a, 1); a += __shfl_xor(a, 2);
                a += __shfl_xor(a, 4); a += __shfl_xor(a, 8);
                if (l2 == 0) Qb[r] = a + attn_b[r];
            }
            __syncthreads();
            qp = Qb;
        }

        // e[s] = sum_m v[m] * tanh(q[m] + C[s][m]); float4, 16 lanes/slot
        const float* crow = &Cs[sidx * kCsStride];
        float acc = 0.f;
#pragma unroll
        for (int j = 0; j < 8; ++j) {
            int m = ml * 4 + j * 64;
            float4 q4 = *(const float4*)(qp + m);
            float4 c4 = *(const float4*)&crow[m];
            float4 v4 = *(const float4*)&vs[m];
            acc = fmaf(v4.x, tanh_fast(q4.x + c4.x), acc);
            acc = fmaf(v4.y, tanh_fast(q4.y + c4.y), acc);
            acc = fmaf(v4.z, tanh_fast(q4.z + c4.z), acc);
            acc = fmaf(v4.w, tanh_fast(q4.w + c4.w), acc);
        }
        acc += __shfl_xor(acc, 1); acc += __shfl_xor(acc, 2);
        acc += __shfl_xor(acc, 4); acc += __shfl_xor(acc, 8);
        if (ml == 0) e_sh[sidx] = acc;
        __syncthreads();

        // wave 0: softmax + empty mask + gumbel + argmax
        if (tid < 64) {
            int s = tid;
            float ev = (s < kS) ? e_sh[s] : -3.0e38f;
            float mx = ev;
            mx = fmaxf(mx, __shfl_xor(mx, 1));
            mx = fmaxf(mx, __shfl_xor(mx, 2));
            mx = fmaxf(mx, __shfl_xor(mx, 4));
            mx = fmaxf(mx, __shfl_xor(mx, 8));
            float w = (s < kS) ? __expf(ev - mx) : 0.f;
            float sm = w;
            sm += __shfl_xor(sm, 1); sm += __shfl_xor(sm, 2);
            sm += __shfl_xor(sm, 4); sm += __shfl_xor(sm, 8);
            w = w / sm;
            w += 10.0f * ((s < kS) ? empty_sh[s] : 0.f);
            float z;
            if (s < kS) {
                float u = gumbel_u[(size_t)(b * kN + t) * kS + s];
                u = fminf(fmaxf(u, 1e-20f), 1.0f);
                float g = -logf(-logf(u) + 1e-20f);
                z = w + g;            // tau = 1.0
            } else z = -3.0e38f;
            float zm = z;
            zm = fmaxf(zm, __shfl_xor(zm, 1));
            zm = fmaxf(zm, __shfl_xor(zm, 2));
            zm = fmaxf(zm, __shfl_xor(zm, 4));
            zm = fmaxf(zm, __shfl_xor(zm, 8));
            unsigned long long bal = __ballot(z == zm) & 0xFFFFull;
            if (s == 0) k_sh = __ffsll(bal) - 1;   // first-max (jnp.argmax)
        }
        __syncthreads();

        const int k = k_sh;
        if (tid < kS) out_log[(size_t)(b * kN + t) * kS + tid] = (tid == k) ? 1.f : 0.f;
        if (tid == 0) {
            float mv = states_mask[b * kN + t];
            wk_sh = (k < kSlots && mv != 0.0f) ? k : -1;
            nz_sh = 0;
        }
        __syncthreads();

        const int wk = wk_sh;
        if (wk >= 0) {
            if (pos < kCap) {
                // cached: C-row copy + precomputed nz flag
                Cs[wk * kCsStride + tid] = cwCache[(size_t)pos * kM + tid];
                Cs[wk * kCsStride + 256 + tid] = cwCache[(size_t)pos * kM + 256 + tid];
                if (tid == 0) {
                    slot_src[wk] = t;
                    empty_sh[wk] = stepNz[pos] ? 0.f : 1.f;
                }
            } else {
                // fallback: inline cw GEMV from staged Xb (dead code normally)
                if (Xb[tid] != 0.f || Xb[256 + tid] != 0.f) nz_sh = 1;
                __syncthreads();
                const int g2 = tid >> 4, l2 = tid & 15;
                for (int r0 = 0; r0 < kM; r0 += 16) {
                    int r = r0 + g2;
                    const float* wr = W + (size_t)r * kW + 1024;
                    float ca = 0.f;
                    for (int k2 = l2 * 4; k2 < kM; k2 += 64) {
                        float4 w4 = *(const float4*)(wr + k2);
                        float4 x4 = *(const float4*)&Xb[k2];
                        ca = fmaf(w4.x, x4.x, ca); ca = fmaf(w4.y, x4.y, ca);
                        ca = fmaf(w4.z, x4.z, ca); ca = fmaf(w4.w, x4.w, ca);
                    }
                    ca += __shfl_xor(ca, 1); ca += __shfl_xor(ca, 2);
                    ca += __shfl_xor(ca, 4); ca += __shfl_xor(ca, 8);
                    if (l2 == 0) Cs[wk * kCsStride + r] = ca;
                }
                __syncthreads();
                if (tid == 0) {
                    slot_src[wk] = t;
                    empty_sh[wk] = nz_sh ? 0.f : 1.f;
                }
            }
        }
        __syncthreads();
    }

    // epilogue: overwrite written slots only (bulk copy already done)
    for (int s = 0; s < kSlots; ++s) {
        int ts = slot_src[s];
        if (ts >= 0) {
            float* dst = out_hm + (size_t)(b * kSlots + s) * kM;
            dst[tid] = states[(size_t)(b * kN + ts) * kM + tid];
            dst[tid + 256] = states[(size_t)(b * kN + ts) * kM + tid + 256];
        }
    }
}

// ---------------------------------------------------------------------------
extern "C" void kernel_launch(void* const* d_in, const int* in_sizes, int n_in,
                              void* d_out, int out_size, void* d_ws, size_t ws_size,
                              hipStream_t stream)
{
    const float* his_mem      = (const float*)d_in[0];
    const float* states       = (const float*)d_in[1];
    const float* states_mask  = (const float*)d_in[2];
    const float* global_trace = (const float*)d_in[3];
    const float* null_mem     = (const float*)d_in[4];
    const float* gumbel_u     = (const float*)d_in[5];
    const float* attn_W       = (const float*)d_in[6];
    const float* attn_b       = (const float*)d_in[7];
    const float* v            = (const float*)d_in[8];

    // ws layout (~40.6 MB):
    //   C0      [4096*512] f32   ( 8 MB)
    //   qCache  [8192*512] f32   (16 MB)
    //   cwCache [8192*512] f32   (16 MB)
    //   cnt[256] i32 | total[16] i32            <- zeroed by one memset
    //   empty0[4096] i32 | ambBatch[256] i32 | stepNz[8192] i32
    //   listPos[32768] i32 | list[32768] u32 | amb[32768] u8
    float* C0 = (float*)d_ws;
    float* qCache = C0 + (size_t)kB * kS * kM;
    float* cwCache = qCache + (size_t)kCap * kM;
    int* cnt = (int*)(cwCache + (size_t)kCap * kM);
    int* total = cnt + kB;
    int* empty0 = total + 16;
    int* ambBatch = empty0 + kB * kS;
    int* stepNz = ambBatch + kB;
    int* listPos = stepNz + kCap;
    unsigned* list = (unsigned*)(listPos + kB * kN);
    unsigned char* amb = (unsigned char*)(list + kB * kN);

    hipMemsetAsync(cnt, 0, (kB + 16) * sizeof(int), stream);
    prep1_k<<<kB, 256, 0, stream>>>(his_mem, null_mem, gumbel_u, (float*)d_out,
                                    empty0, cnt, total, list, listPos, ambBatch,
                                    amb);
    prep2_k<<<2560, 256, 0, stream>>>(attn_W, his_mem, null_mem, states,
                                      global_trace, attn_b, total, ambBatch,
                                      list, C0, qCache, cwCache, stepNz);
    phaseB_k<<<kB, 256, 0, stream>>>(C0, empty0, amb, cnt, listPos, qCache,
                                     cwCache, stepNz, states, states_mask,
                                     gumbel_u, global_trace, attn_W, attn_b, v,
                                     (float*)d_out);
}